// Round 10
// baseline (62.479 us; speedup 1.0000x reference)
//
#include <hip/hip_runtime.h>

// Volume rendering (NeRF-style) for sorted ray_id segments.
// Outputs concatenated in d_out (f32):
//   pred_rgb (R,3) | pred_depth (R,1) | bg_transmittance (R,1) | weight (N,1)
//
// Structure: persistent-ish waves, 32 rays/wave, processed as 16 groups of 2
// with a depth-2 software pipeline. ALL hot-path loads are inline-asm VMEM so
// vmcnt counting is exact; counted s_waitcnt vmcnt(10) overlaps group g+1's
// loads with group g's compute.

#define NGROUP 16   // groups per wave
#define RPW 2       // rays per group  -> 32 rays/wave

typedef float __attribute__((ext_vector_type(2))) f32x2;
typedef float __attribute__((ext_vector_type(4))) f32x4;

struct Pay { f32x2 sg, zv, dt, c45; f32x4 c03; };  // 12 floats per ray

// ---- DPP helpers (VALU cross-lane, no LDS) ----
template <int CTRL, int ROW_MASK>
__device__ __forceinline__ float dpp_add(float x) {
    int t = __builtin_amdgcn_update_dpp(0, __float_as_int(x), CTRL, ROW_MASK, 0xf, true);
    return x + __int_as_float(t);
}

// wave64 inclusive prefix sum; lane 63 holds the total
__device__ __forceinline__ float wave_incl_scan(float x) {
    x = dpp_add<0x111, 0xf>(x);  // row_shr:1
    x = dpp_add<0x112, 0xf>(x);  // row_shr:2
    x = dpp_add<0x114, 0xf>(x);  // row_shr:4
    x = dpp_add<0x118, 0xf>(x);  // row_shr:8
    x = dpp_add<0x142, 0xa>(x);  // row_bcast:15 -> rows 1,3
    x = dpp_add<0x143, 0xc>(x);  // row_bcast:31 -> rows 2,3
    return x;
}

__device__ __forceinline__ float readlane_f32(float x, int lane) {
    return __int_as_float(__builtin_amdgcn_readlane(__float_as_int(x), lane));
}

__global__ void compute_starts_kernel(const int* __restrict__ ray_id,
                                      int n_samples, int n_rays,
                                      int* __restrict__ starts) {
    const int t = blockIdx.x * blockDim.x + threadIdx.x;
    const int stride = gridDim.x * blockDim.x;
    if (t == 0) {
        const int first = ray_id[0];
        for (int r = 0; r <= first; ++r) starts[r] = 0;
        const int last = ray_id[n_samples - 1];
        for (int r = last + 1; r <= n_rays; ++r) starts[r] = n_samples;
    }
    for (int g = t; g * 4 < n_samples; g += stride) {
        const int i4 = g * 4;
        const int4 v = *reinterpret_cast<const int4*>(ray_id + i4);
        const int prev = (i4 == 0) ? v.x : ray_id[i4 - 1];
        const int vals[5] = {prev, v.x, v.y, v.z, v.w};
        #pragma unroll
        for (int j = 0; j < 4; ++j) {
            const int p = vals[j], c = vals[j + 1];
            if (c != p) {
                for (int r = p + 1; r <= c; ++r) starts[r] = i4 + j;
            }
        }
    }
}

// issue one ray's 5 loads (asm volatile: cannot be moved or split)
__device__ __forceinline__ void issue_ray(Pay& p,
                                          const float* __restrict__ sigma_in,
                                          const float* __restrict__ z_in,
                                          const float* __restrict__ dt_in,
                                          const float* __restrict__ rgb,
                                          int s0, int lane, int imax2) {
    const int il = min(s0 + 2 * lane, imax2);
    const float* a = sigma_in + il;
    const float* b = z_in + il;
    const float* c = dt_in + il;
    const float* d = rgb + 3 * (size_t)il;
    asm volatile("global_load_dwordx2 %0, %1, off" : "=v"(p.sg)  : "v"(a));
    asm volatile("global_load_dwordx2 %0, %1, off" : "=v"(p.zv)  : "v"(b));
    asm volatile("global_load_dwordx2 %0, %1, off" : "=v"(p.dt)  : "v"(c));
    asm volatile("global_load_dwordx4 %0, %1, off" : "=v"(p.c03) : "v"(d));
    asm volatile("global_load_dwordx2 %0, %1, off" : "=v"(p.c45) : "v"(d + 4));
}

// rare-path (rays > 128 samples): one 128-sample pass with running carry
__device__ __forceinline__ void process_pass128_rare(
    const float* __restrict__ sigma_in, const float* __restrict__ z_in,
    const float* __restrict__ dt_in, const float* __restrict__ rgb,
    int base, int s1, int lane, int use_exit, float texit, int n_samples,
    float& csum, float& carry,
    float& aR, float& aG, float& aB, float& aD,
    float* __restrict__ out_w)
{
    const int i0 = base + 2 * lane, i1 = i0 + 1;
    const int il = min(i0, n_samples - 2);
    float sgx = sigma_in[il],     sgy = sigma_in[il + 1];
    float zvx = z_in[il],         zvy = z_in[il + 1];
    float dtx = dt_in[il],        dty = dt_in[il + 1];
    float c0 = rgb[3 * (size_t)il + 0], c1 = rgb[3 * (size_t)il + 1], c2 = rgb[3 * (size_t)il + 2];
    float c3 = rgb[3 * (size_t)il + 3], c4 = rgb[3 * (size_t)il + 4], c5 = rgb[3 * (size_t)il + 5];
    if (i0 > n_samples - 2) { sgx = sgy; zvx = zvy; dtx = dty; c0 = c3; c1 = c4; c2 = c5; }
    if (use_exit && i0 == s1 - 1) dtx = texit - zvx;
    if (use_exit && i1 == s1 - 1) dty = texit - zvy;
    const float e0 = (i0 < s1) ? sgx * dtx : 0.f;
    const float e1 = (i1 < s1) ? sgy * dty : 0.f;
    const float t1 = csum + wave_incl_scan(e0 + e1);
    const float v0 = __expf(-(t1 - e1));
    const float v1 = __expf(-t1);
    const int vpi = __builtin_amdgcn_update_dpp(__float_as_int(carry), __float_as_int(v1),
                                                0x138 /*wave_shr:1*/, 0xf, 0xf, false);
    const float w0 = __int_as_float(vpi) - v0;
    const float w1 = v0 - v1;
    if (i0 < s1) out_w[i0] = w0;
    if (i1 < s1) out_w[i1] = w1;
    aR += w0 * c0 + w1 * c3;
    aG += w0 * c1 + w1 * c4;
    aB += w0 * c2 + w1 * c5;
    aD += w0 * zvx + w1 * zvy;
    csum  = readlane_f32(t1, 63);
    carry = readlane_f32(v1, 63);
}

// full per-ray compute from a loaded Pay (data must be vmcnt-retired already)
__device__ __forceinline__ void compute_ray(
    const Pay& p, int ray, int s0, int s1, int lane, int use_exit, float texit,
    int n_samples, int n_rays,
    const float* __restrict__ sigma_in, const float* __restrict__ z_in,
    const float* __restrict__ dt_in, const float* __restrict__ rgb,
    float* __restrict__ out_rgb, float* __restrict__ out_depth,
    float* __restrict__ out_bg, float* __restrict__ out_w)
{
    const int i0 = s0 + 2 * lane, i1 = i0 + 1;
    const bool clamped = i0 > n_samples - 2;   // sample i0 sits in the .y slot
    const float sgx = clamped ? p.sg.y : p.sg.x;
    const float sgy = p.sg.y;
    const float zvx = clamped ? p.zv.y : p.zv.x;
    const float zvy = p.zv.y;
    float dt0 = clamped ? p.dt.y : p.dt.x;
    float dt1 = p.dt.y;
    const float cc0 = clamped ? p.c03.w : p.c03.x;
    const float cc1 = clamped ? p.c45.x : p.c03.y;
    const float cc2 = clamped ? p.c45.y : p.c03.z;
    const float cc3 = p.c03.w, cc4 = p.c45.x, cc5 = p.c45.y;
    if (use_exit && i0 == s1 - 1) dt0 = texit - zvx;
    if (use_exit && i1 == s1 - 1) dt1 = texit - zvy;
    const float e0 = (i0 < s1) ? sgx * dt0 : 0.f;
    const float e1 = (i1 < s1) ? sgy * dt1 : 0.f;
    const float t1 = wave_incl_scan(e0 + e1);       // csum = 0 on pass 1
    const float v0 = __expf(-(t1 - e1));
    const float v1 = __expf(-t1);
    const int vpi = __builtin_amdgcn_update_dpp(0x3f800000 /*1.0f*/, __float_as_int(v1),
                                                0x138 /*wave_shr:1*/, 0xf, 0xf, false);
    const float w0 = __int_as_float(vpi) - v0;
    const float w1 = v0 - v1;
    float accR = w0 * cc0 + w1 * cc3;
    float accG = w0 * cc1 + w1 * cc4;
    float accB = w0 * cc2 + w1 * cc5;
    float accD = w0 * zvx + w1 * zvy;
    if (i0 < s1) out_w[i0] = w0;
    if (i1 < s1) out_w[i1] = w1;
    float bg = readlane_f32(v1, 63);

    if (__builtin_expect(s0 + 128 < s1, 0)) {       // rays > 128 samples: ~never
        float csum  = readlane_f32(t1, 63);
        float carry = bg;
        for (int base = s0 + 128; base < s1; base += 128) {
            process_pass128_rare(sigma_in, z_in, dt_in, rgb, base, s1, lane,
                                 use_exit, texit, n_samples,
                                 csum, carry, accR, accG, accB, accD, out_w);
        }
        bg = carry;
    }

    const float r = wave_incl_scan(accR);
    const float g = wave_incl_scan(accG);
    const float b = wave_incl_scan(accB);
    const float d = wave_incl_scan(accD);
    if (lane == 63 && ray < n_rays) {
        out_rgb[3 * ray + 0] = r;
        out_rgb[3 * ray + 1] = g;
        out_rgb[3 * ray + 2] = b;
        out_depth[ray] = d;
        out_bg[ray]    = bg;
    }
}

__global__ __launch_bounds__(256, 4) void render_kernel(
    const float* __restrict__ rgb,       // (N,3)
    const float* __restrict__ sigma_in,  // (N,1)
    const float* __restrict__ z_in,      // (N,)
    const float* __restrict__ dt_in,     // (N,)
    const float* __restrict__ t_exit,    // (R,1)
    const int*  __restrict__ use_exit_p, // scalar
    const int*  __restrict__ starts,     // (R+1,)
    float* __restrict__ out_rgb,         // (R,3)
    float* __restrict__ out_depth,       // (R,)
    float* __restrict__ out_bg,          // (R,)
    float* __restrict__ out_w,           // (N,)
    int n_rays, int n_samples)
{
    const int wave = threadIdx.x >> 6;
    const int lane = threadIdx.x & 63;
    const int wid  = blockIdx.x * 4 + wave;
    const int r0   = wid * (NGROUP * RPW);            // 32 consecutive rays
    const int use_exit = __builtin_amdgcn_readfirstlane(*use_exit_p);
    const int imax2 = n_samples - 2;

    // ---- prologue: 33 boundaries + 32 t_exits in TWO vector loads ----
    int sv; float tv;
    {
        const int* sp = starts + min(r0 + lane, n_rays);
        asm volatile("global_load_dword %0, %1, off" : "=v"(sv) : "v"(sp));
        const float* tp = t_exit + min(r0 + lane, n_rays - 1);
        asm volatile("global_load_dword %0, %1, off" : "=v"(tv) : "v"(tp));
    }
    asm volatile("s_waitcnt vmcnt(0)" ::: "memory");
    __builtin_amdgcn_sched_barrier(0);

    // ---- fill pipeline: groups 0 (A) and 1 (B) ----
    Pay A0, A1, B0, B1;
    issue_ray(A0, sigma_in, z_in, dt_in, rgb, __builtin_amdgcn_readlane(sv, 0), lane, imax2);
    issue_ray(A1, sigma_in, z_in, dt_in, rgb, __builtin_amdgcn_readlane(sv, 1), lane, imax2);
    issue_ray(B0, sigma_in, z_in, dt_in, rgb, __builtin_amdgcn_readlane(sv, 2), lane, imax2);
    issue_ray(B1, sigma_in, z_in, dt_in, rgb, __builtin_amdgcn_readlane(sv, 3), lane, imax2);

    int g = 0;
    #pragma unroll 1
    for (int it = 0; it < (NGROUP - 2) / 2; ++it) {
        {   // group g from A; refill A with group g+2
            const int j = 2 * g;
            asm volatile("s_waitcnt vmcnt(10)" ::: "memory");
            __builtin_amdgcn_sched_barrier(0);
            const int s0a = __builtin_amdgcn_readlane(sv, j);
            const int s1a = __builtin_amdgcn_readlane(sv, j + 1);
            const int s2a = __builtin_amdgcn_readlane(sv, j + 2);
            const float tx0 = readlane_f32(tv, j);
            const float tx1 = readlane_f32(tv, j + 1);
            compute_ray(A0, r0 + j,     s0a, s1a, lane, use_exit, tx0, n_samples, n_rays,
                        sigma_in, z_in, dt_in, rgb, out_rgb, out_depth, out_bg, out_w);
            compute_ray(A1, r0 + j + 1, s1a, s2a, lane, use_exit, tx1, n_samples, n_rays,
                        sigma_in, z_in, dt_in, rgb, out_rgb, out_depth, out_bg, out_w);
            issue_ray(A0, sigma_in, z_in, dt_in, rgb,
                      __builtin_amdgcn_readlane(sv, j + 4), lane, imax2);
            issue_ray(A1, sigma_in, z_in, dt_in, rgb,
                      __builtin_amdgcn_readlane(sv, j + 5), lane, imax2);
        }
        {   // group g+1 from B; refill B with group g+3
            const int j = 2 * g + 2;
            asm volatile("s_waitcnt vmcnt(10)" ::: "memory");
            __builtin_amdgcn_sched_barrier(0);
            const int s0b = __builtin_amdgcn_readlane(sv, j);
            const int s1b = __builtin_amdgcn_readlane(sv, j + 1);
            const int s2b = __builtin_amdgcn_readlane(sv, j + 2);
            const float tx0 = readlane_f32(tv, j);
            const float tx1 = readlane_f32(tv, j + 1);
            compute_ray(B0, r0 + j,     s0b, s1b, lane, use_exit, tx0, n_samples, n_rays,
                        sigma_in, z_in, dt_in, rgb, out_rgb, out_depth, out_bg, out_w);
            compute_ray(B1, r0 + j + 1, s1b, s2b, lane, use_exit, tx1, n_samples, n_rays,
                        sigma_in, z_in, dt_in, rgb, out_rgb, out_depth, out_bg, out_w);
            issue_ray(B0, sigma_in, z_in, dt_in, rgb,
                      __builtin_amdgcn_readlane(sv, j + 4), lane, imax2);
            issue_ray(B1, sigma_in, z_in, dt_in, rgb,
                      __builtin_amdgcn_readlane(sv, j + 5), lane, imax2);
        }
        g += 2;
    }

    // ---- epilogue: group NGROUP-2 (A), then NGROUP-1 (B) ----
    {
        const int j = 2 * (NGROUP - 2);
        asm volatile("s_waitcnt vmcnt(10)" ::: "memory");
        __builtin_amdgcn_sched_barrier(0);
        const int s0a = __builtin_amdgcn_readlane(sv, j);
        const int s1a = __builtin_amdgcn_readlane(sv, j + 1);
        const int s2a = __builtin_amdgcn_readlane(sv, j + 2);
        compute_ray(A0, r0 + j,     s0a, s1a, lane, use_exit, readlane_f32(tv, j), n_samples, n_rays,
                    sigma_in, z_in, dt_in, rgb, out_rgb, out_depth, out_bg, out_w);
        compute_ray(A1, r0 + j + 1, s1a, s2a, lane, use_exit, readlane_f32(tv, j + 1), n_samples, n_rays,
                    sigma_in, z_in, dt_in, rgb, out_rgb, out_depth, out_bg, out_w);
    }
    {
        const int j = 2 * (NGROUP - 1);
        asm volatile("s_waitcnt vmcnt(0)" ::: "memory");
        __builtin_amdgcn_sched_barrier(0);
        const int s0b = __builtin_amdgcn_readlane(sv, j);
        const int s1b = __builtin_amdgcn_readlane(sv, j + 1);
        const int s2b = __builtin_amdgcn_readlane(sv, j + 2);
        compute_ray(B0, r0 + j,     s0b, s1b, lane, use_exit, readlane_f32(tv, j), n_samples, n_rays,
                    sigma_in, z_in, dt_in, rgb, out_rgb, out_depth, out_bg, out_w);
        compute_ray(B1, r0 + j + 1, s1b, s2b, lane, use_exit, readlane_f32(tv, j + 1), n_samples, n_rays,
                    sigma_in, z_in, dt_in, rgb, out_rgb, out_depth, out_bg, out_w);
    }
}

extern "C" void kernel_launch(void* const* d_in, const int* in_sizes, int n_in,
                              void* d_out, int out_size, void* d_ws, size_t ws_size,
                              hipStream_t stream) {
    const float* rgb     = (const float*)d_in[0];
    const float* sigma   = (const float*)d_in[1];
    const float* z       = (const float*)d_in[2];
    const float* dt      = (const float*)d_in[3];
    const int*   ray_id  = (const int*)d_in[4];
    const float* t_exit  = (const float*)d_in[5];
    const int*   use_ex  = (const int*)d_in[6];

    const int n_samples = in_sizes[2];   // samples_z flat count
    const int n_rays    = in_sizes[5];   // ray_t_exit flat count

    int* starts = (int*)d_ws;            // (n_rays + 1) ints

    float* out      = (float*)d_out;
    float* out_rgb  = out;
    float* out_dep  = out + (size_t)3 * n_rays;
    float* out_bg   = out + (size_t)4 * n_rays;
    float* out_w    = out + (size_t)5 * n_rays;

    compute_starts_kernel<<<2048, 256, 0, stream>>>(ray_id, n_samples, n_rays, starts);

    const int rays_per_block = 4 * NGROUP * RPW;   // 4 waves x 32 rays = 128
    const int blocks = (n_rays + rays_per_block - 1) / rays_per_block;
    render_kernel<<<blocks, 256, 0, stream>>>(rgb, sigma, z, dt, t_exit, use_ex,
                                              starts, out_rgb, out_dep, out_bg,
                                              out_w, n_rays, n_samples);
}

// Round 11
// 53.128 us; speedup vs baseline: 1.1760x; 1.1760x over previous
//
#include <hip/hip_runtime.h>

// Volume rendering (NeRF-style) for sorted ray_id segments.
// Outputs concatenated in d_out (f32):
//   pred_rgb (R,3) | pred_depth (R,1) | bg_transmittance (R,1) | weight (N,1)
//
// Structure (proven best at 52.8 us e2e): 4 rays/wave, 1 sample/lane,
// chunk-1 + chunk-2 data loads issued upfront (compiler may interleave),
// DPP wave scans, 2-exp per sample formulation.

#define RPW 4  // rays per wave

// ---- DPP helpers (VALU cross-lane, no LDS) ----
template <int CTRL, int ROW_MASK>
__device__ __forceinline__ float dpp_add(float x) {
    int t = __builtin_amdgcn_update_dpp(0, __float_as_int(x), CTRL, ROW_MASK, 0xf, true);
    return x + __int_as_float(t);
}

// wave64 inclusive prefix sum (6 VALU ops); lane 63 holds the total
__device__ __forceinline__ float wave_incl_scan(float x) {
    x = dpp_add<0x111, 0xf>(x);  // row_shr:1
    x = dpp_add<0x112, 0xf>(x);  // row_shr:2
    x = dpp_add<0x114, 0xf>(x);  // row_shr:4
    x = dpp_add<0x118, 0xf>(x);  // row_shr:8
    x = dpp_add<0x142, 0xa>(x);  // row_bcast:15 -> rows 1,3
    x = dpp_add<0x143, 0xc>(x);  // row_bcast:31 -> rows 2,3
    return x;
}

__device__ __forceinline__ float readlane_f32(float x, int lane) {
    return __int_as_float(__builtin_amdgcn_readlane(__float_as_int(x), lane));
}

__global__ void compute_starts_kernel(const int* __restrict__ ray_id,
                                      int n_samples, int n_rays,
                                      int* __restrict__ starts) {
    const int t = blockIdx.x * blockDim.x + threadIdx.x;
    const int stride = gridDim.x * blockDim.x;
    if (t == 0) {
        const int first = ray_id[0];
        for (int r = 0; r <= first; ++r) starts[r] = 0;
        const int last = ray_id[n_samples - 1];
        for (int r = last + 1; r <= n_rays; ++r) starts[r] = n_samples;
    }
    // interior boundaries, 4 samples per thread (n_samples divisible by 4)
    for (int g = t; g * 4 < n_samples; g += stride) {
        const int i4 = g * 4;
        const int4 v = *reinterpret_cast<const int4*>(ray_id + i4);
        const int prev = (i4 == 0) ? v.x : ray_id[i4 - 1];
        const int vals[5] = {prev, v.x, v.y, v.z, v.w};
        #pragma unroll
        for (int j = 0; j < 4; ++j) {
            const int p = vals[j], c = vals[j + 1];
            if (c != p) {
                for (int r = p + 1; r <= c; ++r) starts[r] = i4 + j;
            }
        }
    }
}

// one 64-sample chunk of one ray, data already in registers
__device__ __forceinline__ void process_chunk(
    float sg, float zv, float dtv, float cr, float cg, float cb,
    int base, int s1, int lane, int use_exit, float texit,
    float& csum, float& accR, float& accG, float& accB, float& accD,
    float* __restrict__ out_w)
{
    const int i = base + lane;
    const bool active = i < s1;
    if (use_exit && i == s1 - 1) dtv = texit - zv;   // last sample of the ray
    const float sigdt = active ? sg * dtv : 0.f;
    const float scan  = wave_incl_scan(sigdt);
    const float cexcl = csum + (scan - sigdt);
    const float T     = __expf(-cexcl);
    const float alpha = 1.f - __expf(-sigdt);
    const float w     = alpha * T;                    // 0 for inactive lanes
    if (active) out_w[i] = w;
    accR += w * cr;
    accG += w * cg;
    accB += w * cb;
    accD += w * zv;
    csum += readlane_f32(scan, 63);
}

__global__ __launch_bounds__(256) void render_kernel(
    const float* __restrict__ rgb,       // (N,3)
    const float* __restrict__ sigma_in,  // (N,1)
    const float* __restrict__ z_in,      // (N,)
    const float* __restrict__ dt_in,     // (N,)
    const float* __restrict__ t_exit,    // (R,1)
    const int*  __restrict__ use_exit_p, // scalar
    const int*  __restrict__ starts,     // (R+1,)
    float* __restrict__ out_rgb,         // (R,3)
    float* __restrict__ out_depth,       // (R,)
    float* __restrict__ out_bg,          // (R,)
    float* __restrict__ out_w,           // (N,)
    int n_rays, int n_samples)
{
    const int wave = threadIdx.x >> 6;
    const int lane = threadIdx.x & 63;
    const int wid  = blockIdx.x * (blockDim.x >> 6) + wave;
    const int ray0 = wid * RPW;
    if (ray0 >= n_rays) return;

    // ---- issue ALL loads upfront for max MLP ----
    int s[RPW + 1];
    #pragma unroll
    for (int k = 0; k <= RPW; ++k) {
        s[k] = starts[min(ray0 + k, n_rays)];
    }
    const int use_exit = __builtin_amdgcn_readfirstlane(*use_exit_p);
    float texit[RPW];
    #pragma unroll
    for (int k = 0; k < RPW; ++k) {
        texit[k] = t_exit[min(ray0 + k, n_rays - 1)];
    }

    // chunk-1 and chunk-2 data for all RPW rays: unconditional clamped loads.
    float sg1[RPW], z1[RPW], dt1[RPW], cr1[RPW], cg1[RPW], cb1[RPW];
    float sg2[RPW], z2[RPW], dt2[RPW], cr2[RPW], cg2[RPW], cb2[RPW];
    const int imax = n_samples - 1;
    #pragma unroll
    for (int k = 0; k < RPW; ++k) {
        const int i1 = min(s[k] + lane, imax);
        sg1[k] = sigma_in[i1];
        z1[k]  = z_in[i1];
        dt1[k] = dt_in[i1];
        cr1[k] = rgb[3 * i1 + 0];
        cg1[k] = rgb[3 * i1 + 1];
        cb1[k] = rgb[3 * i1 + 2];
    }
    #pragma unroll
    for (int k = 0; k < RPW; ++k) {
        const int i2 = min(s[k] + 64 + lane, imax);
        sg2[k] = sigma_in[i2];
        z2[k]  = z_in[i2];
        dt2[k] = dt_in[i2];
        cr2[k] = rgb[3 * i2 + 0];
        cg2[k] = rgb[3 * i2 + 1];
        cb2[k] = rgb[3 * i2 + 2];
    }

    // ---- process rays from registers ----
    #pragma unroll
    for (int k = 0; k < RPW; ++k) {
        const int ray = ray0 + k;
        if (ray >= n_rays) break;
        const int s0 = s[k], s1 = s[k + 1];
        float csum = 0.f, accR = 0.f, accG = 0.f, accB = 0.f, accD = 0.f;

        process_chunk(sg1[k], z1[k], dt1[k], cr1[k], cg1[k], cb1[k],
                      s0, s1, lane, use_exit, texit[k],
                      csum, accR, accG, accB, accD, out_w);
        if (s0 + 64 < s1) {
            process_chunk(sg2[k], z2[k], dt2[k], cr2[k], cg2[k], cb2[k],
                          s0 + 64, s1, lane, use_exit, texit[k],
                          csum, accR, accG, accB, accD, out_w);
        }
        // rare: rays longer than 128 samples
        for (int base = s0 + 128; base < s1; base += 64) {
            const int i = min(base + lane, imax);
            const float sg = sigma_in[i];
            const float zv = z_in[i];
            const float dtv = dt_in[i];
            const float cr = rgb[3 * i + 0];
            const float cg = rgb[3 * i + 1];
            const float cb = rgb[3 * i + 2];
            process_chunk(sg, zv, dtv, cr, cg, cb,
                          base, s1, lane, use_exit, texit[k],
                          csum, accR, accG, accB, accD, out_w);
        }

        // per-ray reduction: inclusive scan, lane 63 holds totals
        accR = wave_incl_scan(accR);
        accG = wave_incl_scan(accG);
        accB = wave_incl_scan(accB);
        accD = wave_incl_scan(accD);
        if (lane == 63) {
            out_rgb[3 * ray + 0] = accR;
            out_rgb[3 * ray + 1] = accG;
            out_rgb[3 * ray + 2] = accB;
            out_depth[ray] = accD;
            out_bg[ray]    = __expf(-csum);
        }
    }
}

extern "C" void kernel_launch(void* const* d_in, const int* in_sizes, int n_in,
                              void* d_out, int out_size, void* d_ws, size_t ws_size,
                              hipStream_t stream) {
    const float* rgb     = (const float*)d_in[0];
    const float* sigma   = (const float*)d_in[1];
    const float* z       = (const float*)d_in[2];
    const float* dt      = (const float*)d_in[3];
    const int*   ray_id  = (const int*)d_in[4];
    const float* t_exit  = (const float*)d_in[5];
    const int*   use_ex  = (const int*)d_in[6];

    const int n_samples = in_sizes[2];   // samples_z flat count
    const int n_rays    = in_sizes[5];   // ray_t_exit flat count

    int* starts = (int*)d_ws;            // (n_rays + 1) ints

    float* out      = (float*)d_out;
    float* out_rgb  = out;
    float* out_dep  = out + (size_t)3 * n_rays;
    float* out_bg   = out + (size_t)4 * n_rays;
    float* out_w    = out + (size_t)5 * n_rays;

    compute_starts_kernel<<<2048, 256, 0, stream>>>(ray_id, n_samples, n_rays, starts);

    const int waves_per_block = 4;              // 256 threads
    const int rays_per_block  = waves_per_block * RPW;
    const int blocks = (n_rays + rays_per_block - 1) / rays_per_block;
    render_kernel<<<blocks, 256, 0, stream>>>(rgb, sigma, z, dt, t_exit, use_ex,
                                              starts, out_rgb, out_dep, out_bg,
                                              out_w, n_rays, n_samples);
}